// Round 1
// baseline (222.469 us; speedup 1.0000x reference)
//
#include <hip/hip_runtime.h>

#define SQ 2048
#define SK 2048
#define DD 128
#define NBH 32         // B*H
#define QBLK 64
#define KBLK 32
#define NKT (SK / KBLK)
#define SCALE 0.20884964425119185f
#define SCL2 (SCALE * 1.4426950408889634f)   // fold log2(e): use exp2

typedef __attribute__((ext_vector_type(8))) short short8;
typedef __attribute__((ext_vector_type(4))) short short4v;
typedef __attribute__((ext_vector_type(4))) float f32x4;

// LDS byte offsets (one flat arena; epilogue reuses the front as fp32 scratch)
#define QOFF 0          // Q  bf16 [64][136]  pitch 272 B
#define KOFF 17408      // K  bf16 [32][136]  pitch 272 B
#define VOFF 26112      // Vt bf16 [128][36]  pitch 72 B
#define POFF 35328      // P  bf16 per-wave [16][40] pitch 80 B (4 waves)
#define SMEM_BYTES 40448

__device__ __forceinline__ unsigned short f2bf(float f) {
    unsigned int u = __float_as_uint(f);
    u = u + 0x7fffu + ((u >> 16) & 1u);          // RNE
    return (unsigned short)(u >> 16);
}
__device__ __forceinline__ float bf2f(unsigned short b) {
    return __uint_as_float(((unsigned int)b) << 16);
}

__global__ __launch_bounds__(256, 4) void fattn(
    const float* __restrict__ x1, const float* __restrict__ x2,
    const float* __restrict__ mask, float* __restrict__ out)
{
    __shared__ __align__(16) unsigned char smem[SMEM_BYTES];
    const int tid  = threadIdx.x;
    const int lane = tid & 63, wid = tid >> 6;
    const int c = lane & 15, g = lane >> 4;
    const int bh = blockIdx.x >> 5;      // SQ/QBLK == 32 tiles per (b,h)
    const int qb = blockIdx.x & 31;

    const float* x1b  = x1  + ((size_t)bh * SQ + (size_t)qb * QBLK) * DD;
    const float* x2b  = x2  + (size_t)bh * SK * DD;
    const float* mb   = mask + ((size_t)bh * SQ + (size_t)qb * QBLK) * SK;
    float*       outb = out + ((size_t)bh * SQ + (size_t)qb * QBLK) * DD;

    // ---- stage Q: fp32 -> bf16, pitch 136 bf16 ----
#pragma unroll
    for (int i = 0; i < 8; ++i) {
        int f = tid + 256 * i;
        int row = f >> 5, c4 = (f & 31) * 4;
        float4 v = *(const float4*)(x1b + row * DD + c4);
        unsigned long long w =
              (unsigned long long)f2bf(v.x)
            | ((unsigned long long)f2bf(v.y) << 16)
            | ((unsigned long long)f2bf(v.z) << 32)
            | ((unsigned long long)f2bf(v.w) << 48);
        *(unsigned long long*)(smem + QOFF + row * 272 + c4 * 2) = w;
    }
    __syncthreads();

    // hoist Q fragments (B-operand of S^T): Q[qw+c][ks*32 + 8g + j]
    const int qw = wid * 16;
    short8 qf[4];
#pragma unroll
    for (int ks = 0; ks < 4; ++ks)
        qf[ks] = *(const short8*)(smem + QOFF + (qw + c) * 272 + ks * 64 + 16 * g);

    f32x4 o[8] = {};                 // O^T accum: lane holds O^T[d8*16+4g+r][qw+c]
    float m_run = -1e30f, l_run = 0.f;

    const int d_st = tid & 127;      // staging: lane-linear d
    const int kh   = tid >> 7;       // staging: k half (0/1)
    const int qr = lane >> 2, kr = (lane & 3) * 8;   // mask-RMW mapping
    unsigned char* Pw = smem + POFF + wid * 1280;

    for (int kt = 0; kt < NKT; ++kt) {
        const int kbase = kt * KBLK;

        // prefetch dropout mask for this tile (used post-softmax)
        const float* mrow = mb + (size_t)(qw + qr) * SK + kbase + kr;
        float4 mk0 = *(const float4*)(mrow);
        float4 mk1 = *(const float4*)(mrow + 4);

        __syncthreads();             // previous tile's LDS reads done
        // ---- stage x2 tile -> Krow (row-major) + Vt (transposed) ----
        {
            const float* src = x2b + (size_t)(kbase + kh * 16) * DD + d_st;
            float tv[16];
#pragma unroll
            for (int i = 0; i < 16; ++i) tv[i] = src[i * DD];
            unsigned short tb[16];
#pragma unroll
            for (int i = 0; i < 16; ++i) tb[i] = f2bf(tv[i]);
#pragma unroll
            for (int i = 0; i < 16; ++i)   // Krow[kk][d], 2B writes, ~2-way
                *(unsigned short*)(smem + KOFF + (kh * 16 + i) * 272 + d_st * 2) = tb[i];
#pragma unroll
            for (int j = 0; j < 8; ++j) {  // Vt[d][kk], packed pairs, conflict-free
                unsigned int w = (unsigned int)tb[2 * j] | ((unsigned int)tb[2 * j + 1] << 16);
                *(unsigned int*)(smem + VOFF + d_st * 72 + kh * 32 + j * 4) = w;
            }
        }
        __syncthreads();

        // ---- S^T = K · Q^T  (M=kk=32 -> 2 subtiles, N=q=16, K=d=128) ----
        f32x4 sa0 = {0.f, 0.f, 0.f, 0.f}, sa1 = {0.f, 0.f, 0.f, 0.f};
#pragma unroll
        for (int ks = 0; ks < 4; ++ks) {
            short8 ka0 = *(const short8*)(smem + KOFF + (c)      * 272 + ks * 64 + 16 * g);
            short8 ka1 = *(const short8*)(smem + KOFF + (16 + c) * 272 + ks * 64 + 16 * g);
            sa0 = __builtin_amdgcn_mfma_f32_16x16x32_bf16(ka0, qf[ks], sa0, 0, 0, 0);
            sa1 = __builtin_amdgcn_mfma_f32_16x16x32_bf16(ka1, qf[ks], sa1, 0, 0, 0);
        }

        // ---- online softmax over kk (per q = c; reduce across g) ----
        float s[8];
#pragma unroll
        for (int r = 0; r < 4; ++r) { s[r] = sa0[r] * SCL2; s[4 + r] = sa1[r] * SCL2; }
        float mx = s[0];
#pragma unroll
        for (int i = 1; i < 8; ++i) mx = fmaxf(mx, s[i]);
        mx = fmaxf(mx, __shfl_xor(mx, 16));
        mx = fmaxf(mx, __shfl_xor(mx, 32));
        float mnew = fmaxf(m_run, mx);
        float corr = __builtin_amdgcn_exp2f(m_run - mnew);
        float p[8], lsum = 0.f;
#pragma unroll
        for (int i = 0; i < 8; ++i) { p[i] = __builtin_amdgcn_exp2f(s[i] - mnew); lsum += p[i]; }
        lsum += __shfl_xor(lsum, 16);
        lsum += __shfl_xor(lsum, 32);
        if (__any(mnew > m_run)) {
#pragma unroll
            for (int i = 0; i < 8; ++i) o[i] *= corr;
        }
        l_run = l_run * corr + lsum;
        m_run = mnew;

        // ---- write P (unmasked exp) : contiguous 8B per lane ----
#pragma unroll
        for (int t = 0; t < 2; ++t) {
            unsigned long long w =
                  (unsigned long long)f2bf(p[t * 4 + 0])
                | ((unsigned long long)f2bf(p[t * 4 + 1]) << 16)
                | ((unsigned long long)f2bf(p[t * 4 + 2]) << 32)
                | ((unsigned long long)f2bf(p[t * 4 + 3]) << 48);
            *(unsigned long long*)(Pw + c * 80 + (t * 16 + 4 * g) * 2) = w;
        }
        asm volatile("s_waitcnt lgkmcnt(0)" ::: "memory");

        // ---- dropout-mask RMW on P (coalesced mask loads) ----
        {
            short8 pv = *(const short8*)(Pw + qr * 80 + kr * 2);
            float pf[8];
#pragma unroll
            for (int j = 0; j < 8; ++j) pf[j] = bf2f((unsigned short)pv[j]);
            pf[0] *= mk0.x; pf[1] *= mk0.y; pf[2] *= mk0.z; pf[3] *= mk0.w;
            pf[4] *= mk1.x; pf[5] *= mk1.y; pf[6] *= mk1.z; pf[7] *= mk1.w;
            short8 pwv;
#pragma unroll
            for (int j = 0; j < 8; ++j) pwv[j] = (short)f2bf(pf[j]);
            *(short8*)(Pw + qr * 80 + kr * 2) = pwv;
        }
        asm volatile("s_waitcnt lgkmcnt(0)" ::: "memory");

        // ---- O^T += V^T · P^T (A = Vt rows, B = P rows) ----
        short8 pb = *(const short8*)(Pw + c * 80 + 16 * g);
#pragma unroll
        for (int d8 = 0; d8 < 8; ++d8) {
            const unsigned char* vr = smem + VOFF + (d8 * 16 + c) * 72 + 16 * g;
            short4v vlo = *(const short4v*)(vr);
            short4v vhi = *(const short4v*)(vr + 8);
            short8 va = __builtin_shufflevector(vlo, vhi, 0, 1, 2, 3, 4, 5, 6, 7);
            o[d8] = __builtin_amdgcn_mfma_f32_16x16x32_bf16(va, pb, o[d8], 0, 0, 0);
        }
    }

    // ---- epilogue: normalize, transpose O^T via LDS, coalesced store ----
    __syncthreads();
    float inv_l = 1.0f / l_run;
    float* Of = (float*)(smem) + wid * (128 * 17);
#pragma unroll
    for (int d8 = 0; d8 < 8; ++d8)
#pragma unroll
        for (int r = 0; r < 4; ++r)
            Of[(d8 * 16 + 4 * g + r) * 17 + c] = o[d8][r] * inv_l;
    asm volatile("s_waitcnt lgkmcnt(0)" ::: "memory");
    {
        const int q = lane >> 2, quad = lane & 3;
#pragma unroll
        for (int w = 0; w < 8; ++w) {
            float4 v;
            v.x = Of[(quad * 32 + w * 4 + 0) * 17 + q];
            v.y = Of[(quad * 32 + w * 4 + 1) * 17 + q];
            v.z = Of[(quad * 32 + w * 4 + 2) * 17 + q];
            v.w = Of[(quad * 32 + w * 4 + 3) * 17 + q];
            *(float4*)(outb + (size_t)(qw + q) * DD + quad * 32 + w * 4) = v;
        }
    }
}

extern "C" void kernel_launch(void* const* d_in, const int* in_sizes, int n_in,
                              void* d_out, int out_size, void* d_ws, size_t ws_size,
                              hipStream_t stream) {
    const float* x1   = (const float*)d_in[0];
    const float* x2   = (const float*)d_in[1];
    const float* mask = (const float*)d_in[2];
    fattn<<<dim3(NBH * (SQ / QBLK)), dim3(256), 0, stream>>>(x1, x2, mask, (float*)d_out);
}